// Round 1
// baseline (638.179 us; speedup 1.0000x reference)
//
#include <hip/hip_runtime.h>
#include <hip/hip_bf16.h>
#include <math.h>

#define M_DIM 32768
#define K_DIM 2048
#define N_DIM 2048
#define NBLK2 (N_DIM / 256)   //  8 n-blocks (256-wide) — main path
#define NBLK1 (N_DIM / 128)   // 16 n-blocks (128-wide) — fallback path

typedef __attribute__((ext_vector_type(8))) short short8;   // 8 bf16 = 4 VGPRs
typedef __attribute__((ext_vector_type(4))) float floatx4;  // MFMA C/D

typedef __attribute__((address_space(1))) const void global_cv;
typedef __attribute__((address_space(3))) void lds_v;

// fp32 -> bf16 bits, round-to-nearest-even
static __device__ __forceinline__ unsigned short f2bf(float f) {
    unsigned u = __builtin_bit_cast(unsigned, f);
    unsigned r = (u + 0x7FFFu + ((u >> 16) & 1u)) >> 16;
    return (unsigned short)r;
}

// ---------------------------------------------------------------------------
// cvt_x: x fp32 (M,K) -> bf16 bits, 8 elems/thread, fully coalesced.
// ---------------------------------------------------------------------------
__global__ __launch_bounds__(256) void cvt_x(const float* __restrict__ x,
                                             unsigned short* __restrict__ xb) {
    size_t off = ((size_t)blockIdx.x * 256 + threadIdx.x) * 8;
    float4 a = *(const float4*)(x + off);
    float4 b = *(const float4*)(x + off + 4);
    short8 p;
    p[0] = (short)f2bf(a.x); p[1] = (short)f2bf(a.y);
    p[2] = (short)f2bf(a.z); p[3] = (short)f2bf(a.w);
    p[4] = (short)f2bf(b.x); p[5] = (short)f2bf(b.y);
    p[6] = (short)f2bf(b.z); p[7] = (short)f2bf(b.w);
    *(short8*)(xb + off) = p;
}

// ---------------------------------------------------------------------------
// cvt_wt: W fp32 (K,N) -> Wt bf16 (N,K), 64x64 LDS-tiled transpose.
// ---------------------------------------------------------------------------
__global__ __launch_bounds__(256) void cvt_wt(const float* __restrict__ W,
                                              unsigned short* __restrict__ Wt) {
    __shared__ unsigned short tile[64][65];
    const int t  = threadIdx.x;
    const int nb = blockIdx.x * 64;
    const int kb = blockIdx.y * 64;
#pragma unroll
    for (int i = 0; i < 16; ++i) {
        int e = i * 256 + t;
        int r = e >> 6, c = e & 63;
        tile[r][c] = f2bf(W[(size_t)(kb + r) * N_DIM + nb + c]);
    }
    __syncthreads();
#pragma unroll
    for (int i = 0; i < 16; ++i) {
        int e = i * 256 + t;
        int r = e >> 6, c = e & 63;
        Wt[(size_t)(nb + r) * K_DIM + kb + c] = tile[c][r];
    }
}

// ---------------------------------------------------------------------------
// Round-7: 256x256 tile, 512 threads (8 waves, 2Mx4N), BK=64, double-buffered
// LDS (128 KiB) with counted s_waitcnt vmcnt(8) + raw s_barrier (the next
// tile's 8 DMAs stay in flight across the barrier — no full drain).
//
// Rationale: the 128^2 kernel was staging-BW-bound (AI = 64 FLOP/B staged;
// 4 GB staged @ ~6.3 TB/s == the measured ~640 us). 256^2 doubles AI to
// 128 FLOP/B (2 GB staged). XCD swizzle gives each XCD one 256-wide
// n-column: its 1 MB Wt panel stays L2-resident across all 128 m-blocks;
// xb (134 MB) is L3-resident.
//
// Deposit swizzle (validated round-6 scheme, rescaled): LDS position
// (row, c) holds global k-chunk c ^ (row&7); realized by permuting each
// lane's global source address (global_load_lds deposits lane i at
// base+i*16). Fragment reads at chunk ((s*4+quad)^(lrow&7)) are then
// conflict-free (worst 2-way, free per m136).
// ---------------------------------------------------------------------------
__global__ __launch_bounds__(512, 2) void gemm_lse(const unsigned short* __restrict__ xb,
                                                   const unsigned short* __restrict__ Wt,
                                                   const float* __restrict__ bias,
                                                   float2* __restrict__ part) {
    __shared__ char smem[131072];  // buf0: A@0 B@32K | buf1: A@64K B@96K
    char* lbase = (char*)smem;

    const int t    = threadIdx.x;   // 0..511
    const int w    = t >> 6;        // 0..7
    const int l    = t & 63;
    const int quad = l >> 4;
    const int lrow = l & 15;

    // XCD-aware swizzle: 1024 wgs, 8 XCDs, default dispatch round-robins
    // orig%8 -> XCD. XCD c gets wgid c*128..c*128+127 == n-block c, all
    // 128 m-blocks (contiguous m sweep; B-panel L2-resident per XCD).
    const int wgid = (blockIdx.x & 7) * 128 + (blockIdx.x >> 3);
    const int n0 = (wgid >> 7) * 256;   // 8 n-blocks
    const int m0 = (wgid & 127) * 256;  // 128 m-blocks

    const int wm = (w >> 2) * 128;  // wave m-offset: 0 / 128
    const int wn = (w & 3) * 64;    // wave n-offset: 0 / 64 / 128 / 192

    floatx4 acc[8][4] = {};

    // Deposit geometry: round r, lane t -> LDS chunk c = r*512+t at byte
    // c*16, i.e. (prow, pk_pos) = (r*64 + (t>>3), t&7). Source = global
    // chunk (prow, pk_pos ^ (prow&7));  (t>>3)&7 is r-invariant (r*64).
    const int prow = t >> 3;                  // 0..63
    const int pk   = (t & 7) ^ (prow & 7);
    const unsigned short* ga = xb + (size_t)(m0 + prow) * K_DIM + pk * 8;
    const unsigned short* gb = Wt + (size_t)(n0 + prow) * K_DIM + pk * 8;

    // Fragment read bases: addr = row*128 + ((s*4+quad)^(row&7))*16,
    // row&7 == lrow&7 (wm, im*16 are multiples of 8).
    const int e = lrow & 7;
    const int koff0 = (quad ^ e) * 16;
    const int koff1 = ((quad + 4) ^ e) * 16;
    int arow[8], brow[4];
#pragma unroll
    for (int i = 0; i < 8; ++i) arow[i] = (wm + i * 16 + lrow) * 128;
#pragma unroll
    for (int i = 0; i < 4; ++i) brow[i] = 32768 + (wn + i * 16 + lrow) * 128;

    // 8 DMAs per STAGE (A: 4 rounds x 8KB, B: 4 rounds x 8KB = one 64KB tile)
#define STAGE(BO, KT)                                                          \
    do {                                                                       \
        _Pragma("unroll")                                                      \
        for (int r_ = 0; r_ < 4; ++r_)                                         \
            __builtin_amdgcn_global_load_lds(                                  \
                (global_cv*)(ga + (KT) + r_ * 64 * K_DIM),                     \
                (lds_v*)(lbase + (BO) + t * 16 + r_ * 8192), 16, 0, 0);        \
        _Pragma("unroll")                                                      \
        for (int r_ = 0; r_ < 4; ++r_)                                         \
            __builtin_amdgcn_global_load_lds(                                  \
                (global_cv*)(gb + (KT) + r_ * 64 * K_DIM),                     \
                (lds_v*)(lbase + (BO) + 32768 + t * 16 + r_ * 8192), 16, 0, 0);\
    } while (0)

#define COMPUTE(BO)                                                            \
    do {                                                                       \
        _Pragma("unroll")                                                      \
        for (int s_ = 0; s_ < 2; ++s_) {                                       \
            const int ko_ = s_ ? koff1 : koff0;                                \
            short8 af[8], bv[4];                                               \
            _Pragma("unroll")                                                  \
            for (int i_ = 0; i_ < 8; ++i_)                                     \
                af[i_] = *(const short8*)(lbase + (BO) + arow[i_] + ko_);      \
            _Pragma("unroll")                                                  \
            for (int j_ = 0; j_ < 4; ++j_)                                     \
                bv[j_] = *(const short8*)(lbase + (BO) + brow[j_] + ko_);      \
            _Pragma("unroll")                                                  \
            for (int i_ = 0; i_ < 8; ++i_)                                     \
                _Pragma("unroll")                                              \
                for (int j_ = 0; j_ < 4; ++j_)                                 \
                    acc[i_][j_] = __builtin_amdgcn_mfma_f32_16x16x32_bf16(     \
                        af[i_], bv[j_], acc[i_][j_], 0, 0, 0);                 \
        }                                                                      \
    } while (0)

    // 2-phase pipeline over 32 K-tiles (pair-unrolled so buffer offsets are
    // compile-time). Invariants: a buffer is only re-staged after the barrier
    // that follows its COMPUTE (all waves' ds_reads retired — they feed MFMAs
    // before the barrier); vmcnt(8) leaves only the 8 newest DMAs in flight,
    // so the buffer about to be computed is fully deposited. Stray compiler
    // loads (bias hoist) only make vmcnt(8) MORE conservative, never less.
    STAGE(0, 0);
#pragma unroll 1
    for (int it = 0; it < 16; ++it) {
        const int kt = it * 128;
        STAGE(65536, kt + 64);
        asm volatile("s_waitcnt vmcnt(8)" ::: "memory");
        __builtin_amdgcn_s_barrier();
        asm volatile("" ::: "memory");
        COMPUTE(0);
        asm volatile("" ::: "memory");
        __builtin_amdgcn_s_barrier();   // buf0 reads done in all waves
        asm volatile("" ::: "memory");
        if (it < 15) {
            STAGE(0, kt + 128);
            asm volatile("s_waitcnt vmcnt(8)" ::: "memory");
        } else {
            asm volatile("s_waitcnt vmcnt(0)" ::: "memory");
        }
        __builtin_amdgcn_s_barrier();   // buf1 deposited
        asm volatile("" ::: "memory");
        COMPUTE(65536);
        asm volatile("" ::: "memory");
        __builtin_amdgcn_s_barrier();   // buf1 reads done -> restage next it
        asm volatile("" ::: "memory");
    }
#undef STAGE
#undef COMPUTE

    // ---- Epilogue (validated layout: C col = lrow (n), row = quad*4+reg (m))
    float bvv[4];
#pragma unroll
    for (int in = 0; in < 4; ++in)
        bvv[in] = bias[n0 + wn + in * 16 + lrow];

    float* redf = (float*)smem;  // [4 n-waves][256 rows][2] = 8 KB, post-barrier alias
#pragma unroll
    for (int im = 0; im < 8; ++im) {
#pragma unroll
        for (int r = 0; r < 4; ++r) {
            float v0 = acc[im][0][r] + bvv[0];
            float v1 = acc[im][1][r] + bvv[1];
            float v2 = acc[im][2][r] + bvv[2];
            float v3 = acc[im][3][r] + bvv[3];
            float mx = fmaxf(fmaxf(v0, v1), fmaxf(v2, v3));
#pragma unroll
            for (int s = 1; s < 16; s <<= 1)
                mx = fmaxf(mx, __shfl_xor(mx, s, 64));
            float sm = __expf(v0 - mx) + __expf(v1 - mx) + __expf(v2 - mx) + __expf(v3 - mx);
#pragma unroll
            for (int s = 1; s < 16; s <<= 1)
                sm += __shfl_xor(sm, s, 64);
            if (lrow == ((im * 4 + r) & 15)) {  // one writer lane per quad
                int row = wm + im * 16 + quad * 4 + r;
                redf[((w & 3) * 256 + row) * 2 + 0] = mx;
                redf[((w & 3) * 256 + row) * 2 + 1] = sm;
            }
        }
    }
    __syncthreads();
    if (t < 256) {
        const float2* rp = (const float2*)smem;
        float2 a = rp[t], b = rp[256 + t], c = rp[512 + t], d = rp[768 + t];
        float mm = fmaxf(fmaxf(a.x, b.x), fmaxf(c.x, d.x));
        float ss = a.y * __expf(a.x - mm) + b.y * __expf(b.x - mm) +
                   c.y * __expf(c.x - mm) + d.y * __expf(d.x - mm);
        part[(size_t)(n0 >> 8) * M_DIM + m0 + t] = make_float2(mm, ss);
    }
}

// ---------------------------------------------------------------------------
// Fallback GEMM (round-4-validated, fp32 inputs, 128^2 tiles, 16 partials):
// only used if ws_size can't hold xb+Wt (not the case on this harness).
// ---------------------------------------------------------------------------
__global__ __launch_bounds__(256) void gemm_lse_fb(const float* __restrict__ x,
                                                   const float* __restrict__ W,
                                                   const float* __restrict__ bias,
                                                   float2* __restrict__ part) {
    __shared__ unsigned short lds_a[128 * 32];
    __shared__ unsigned short lds_b[128 * 32];
    __shared__ float red[2][128][2];
    const int t = threadIdx.x, w = t >> 6, l = t & 63, quad = l >> 4, lrow = l & 15;
    const int m0 = blockIdx.y * 128, n0 = blockIdx.x * 128;
    const int wm = (w >> 1) * 64, wn = (w & 1) * 64;
    floatx4 acc[4][4] = {};
    const int ar = t >> 1, ah = (t & 1) * 16;
    const float* gx = x + (size_t)(m0 + ar) * K_DIM + ah;
    const int bn = t & 127, bh = (t >> 7) * 16;
    const float* gw = W + (size_t)bh * N_DIM + n0 + bn;
    for (int kt = 0; kt < K_DIM; kt += 32) {
        float4 xa[4];
#pragma unroll
        for (int q = 0; q < 4; ++q) xa[q] = *(const float4*)(gx + kt + q * 4);
        float wv[16];
#pragma unroll
        for (int j = 0; j < 16; ++j) wv[j] = gw[(size_t)(kt + j) * N_DIM];
        short8 pa0, pa1, pb0, pb1;
#pragma unroll
        for (int j = 0; j < 4; ++j) {
            pa0[j] = (short)f2bf(((const float*)&xa[0])[j]);
            pa0[j + 4] = (short)f2bf(((const float*)&xa[1])[j]);
            pa1[j] = (short)f2bf(((const float*)&xa[2])[j]);
            pa1[j + 4] = (short)f2bf(((const float*)&xa[3])[j]);
        }
#pragma unroll
        for (int j = 0; j < 8; ++j) { pb0[j] = (short)f2bf(wv[j]); pb1[j] = (short)f2bf(wv[j + 8]); }
        __syncthreads();
        *(short8*)&lds_a[ar * 32 + ah] = pa0;
        *(short8*)&lds_a[ar * 32 + ah + 8] = pa1;
        *(short8*)&lds_b[bn * 32 + bh] = pb0;
        *(short8*)&lds_b[bn * 32 + bh + 8] = pb1;
        __syncthreads();
        short8 af[4], bf[4];
#pragma unroll
        for (int im = 0; im < 4; ++im)
            af[im] = *(const short8*)((const char*)lds_a + (wm + im * 16 + lrow) * 64 + quad * 16);
#pragma unroll
        for (int in = 0; in < 4; ++in)
            bf[in] = *(const short8*)((const char*)lds_b + (wn + in * 16 + lrow) * 64 + quad * 16);
#pragma unroll
        for (int im = 0; im < 4; ++im)
#pragma unroll
            for (int in = 0; in < 4; ++in)
                acc[im][in] = __builtin_amdgcn_mfma_f32_16x16x32_bf16(af[im], bf[in], acc[im][in], 0, 0, 0);
    }
    float bvv[4];
#pragma unroll
    for (int in = 0; in < 4; ++in) bvv[in] = bias[n0 + wn + in * 16 + lrow];
#pragma unroll
    for (int im = 0; im < 4; ++im) {
#pragma unroll
        for (int r = 0; r < 4; ++r) {
            float v0 = acc[im][0][r] + bvv[0], v1 = acc[im][1][r] + bvv[1];
            float v2 = acc[im][2][r] + bvv[2], v3 = acc[im][3][r] + bvv[3];
            float mx = fmaxf(fmaxf(v0, v1), fmaxf(v2, v3));
#pragma unroll
            for (int s = 1; s < 16; s <<= 1) mx = fmaxf(mx, __shfl_xor(mx, s, 64));
            float sm = __expf(v0 - mx) + __expf(v1 - mx) + __expf(v2 - mx) + __expf(v3 - mx);
#pragma unroll
            for (int s = 1; s < 16; s <<= 1) sm += __shfl_xor(sm, s, 64);
            if (lrow == im * 4 + r) {
                int row = wm + im * 16 + quad * 4 + r;
                red[w & 1][row][0] = mx;
                red[w & 1][row][1] = sm;
            }
        }
    }
    __syncthreads();
    if (t < 128) {
        float ma = red[0][t][0], sa = red[0][t][1];
        float mb = red[1][t][0], sb = red[1][t][1];
        float mm = fmaxf(ma, mb);
        float ss = sa * __expf(ma - mm) + sb * __expf(mb - mm);
        part[(size_t)blockIdx.x * M_DIM + m0 + t] = make_float2(mm, ss);
    }
}

// ---------------------------------------------------------------------------
// Merge NB partials per row, logsumexp, leaky x2, erf-GELU x2. FLOAT out.
// ---------------------------------------------------------------------------
template <int NB>
__global__ __launch_bounds__(256) void lse_final(const float2* __restrict__ part,
                                                 float* __restrict__ out) {
    const int r = blockIdx.x * 256 + threadIdx.x;
    float2 p[NB];
    float mm = -INFINITY;
#pragma unroll
    for (int nb = 0; nb < NB; ++nb) {
        p[nb] = part[(size_t)nb * M_DIM + r];
        mm = fmaxf(mm, p[nb].x);
    }
    float ss = 0.f;
#pragma unroll
    for (int nb = 0; nb < NB; ++nb)
        ss += p[nb].y * __expf(p[nb].x - mm);

    float z;
    if (isnan(mm)) {
        z = 12345.0f;               // tripwire A (inert when correct)
    } else if (!(ss > 0.f)) {
        z = mm;                     // tripwire B (inert when correct)
    } else {
        z = mm + logf(ss);
    }
    z = z > 0.f ? z : 0.01f * z;
    z = z > 0.f ? z : 0.01f * z;
    z = 0.5f * z * (1.f + erff(z * 0.70710678118654752f));
    z = 0.5f * z * (1.f + erff(z * 0.70710678118654752f));
    out[r] = z;
}

// ---------------------------------------------------------------------------
extern "C" void kernel_launch(void* const* d_in, const int* in_sizes, int n_in,
                              void* d_out, int out_size, void* d_ws, size_t ws_size,
                              hipStream_t stream) {
    const float* x    = (const float*)d_in[0];
    const float* W    = (const float*)d_in[1];
    const float* bias = (const float*)d_in[2];
    float* out = (float*)d_out;

    const size_t xb_bytes   = (size_t)M_DIM * K_DIM * 2;   // 134 MB
    const size_t wt_bytes   = (size_t)N_DIM * K_DIM * 2;   //   8 MB
    const size_t part_bytes = (size_t)NBLK2 * M_DIM * 8;   //   2 MB

    if (ws_size >= xb_bytes + wt_bytes + part_bytes) {
        unsigned short* xb = (unsigned short*)d_ws;
        unsigned short* Wt = (unsigned short*)((char*)d_ws + xb_bytes);
        float2* part = (float2*)((char*)d_ws + xb_bytes + wt_bytes);
        cvt_x<<<(int)((size_t)M_DIM * K_DIM / (8 * 256)), 256, 0, stream>>>(x, xb);
        cvt_wt<<<dim3(N_DIM / 64, K_DIM / 64), 256, 0, stream>>>(W, Wt);
        gemm_lse<<<dim3((N_DIM / 256) * (M_DIM / 256)), 512, 0, stream>>>(xb, Wt, bias, part);
        lse_final<NBLK2><<<M_DIM / 256, 256, 0, stream>>>(part, out);
    } else {
        float2* part = (float2*)d_ws;
        gemm_lse_fb<<<dim3(N_DIM / 128, M_DIM / 128), 256, 0, stream>>>(x, W, bias, part);
        lse_final<NBLK1><<<M_DIM / 256, 256, 0, stream>>>(part, out);
    }
}